// Round 7
// baseline (198.240 us; speedup 1.0000x reference)
//
#include <hip/hip_runtime.h>

// Problem: B=2, N=2048, D=1024, H=16, hd=64, WINDOW=256 (causal + local window)
// Inputs FLOAT32, output FLOAT32; internal compute bf16 MFMA.
//
// Round 7: QKV GEMM back to 128x128 tiles (64 MFMA/K-iter, m97 structure) now
// that XCD swizzle fixed the L2 thrash. V projection writes V^T [B,H,hd,N]
// directly (epilogue is scalar scatter either way), so attention stages V^T
// with vector loads + ds_write_b128 instead of 96 scalar ds_write_b16/thread.
// K staging via global_load_lds.

typedef unsigned short ushort_t;
typedef __bf16 bf16x8 __attribute__((ext_vector_type(8)));
typedef float f32x4 __attribute__((ext_vector_type(4)));
typedef unsigned short ushort8 __attribute__((ext_vector_type(8)));

#define LOG2E 1.4426950408889634f

static __device__ __forceinline__ ushort_t f2b(float f) {
    union { float f; unsigned int u; } x;
    x.f = f;
    unsigned int u = x.u;
    unsigned int r = (u + 0x7FFFu + ((u >> 16) & 1u)) >> 16;
    return (ushort_t)r;
}

static __device__ __forceinline__ void store_out(float* p, float v) { *p = v; }
static __device__ __forceinline__ void store_out(ushort_t* p, float v) { *p = f2b(v); }

// async global->LDS 16B copy: per-lane lds addr = wave-base + lane*16
static __device__ __forceinline__ void gload_lds16(const ushort_t* g, ushort_t* l) {
    __builtin_amdgcn_global_load_lds(
        (const __attribute__((address_space(1))) void*)g,
        (__attribute__((address_space(3))) void*)l, 16, 0, 0);
}

// ---------------------------------------------------------------------------
// 0) fp32 -> bf16 elementwise cast (8 elements/thread)
// ---------------------------------------------------------------------------
__global__ __launch_bounds__(256) void cast_f32_bf16_kernel(
    const float* __restrict__ in, ushort_t* __restrict__ out) {
    int i = (blockIdx.x * 256 + threadIdx.x) * 8;
    f32x4 a = *(const f32x4*)&in[i];
    f32x4 b = *(const f32x4*)&in[i + 4];
    ushort8 o;
#pragma unroll
    for (int e = 0; e < 4; e++) o[e] = f2b(a[e]);
#pragma unroll
    for (int e = 0; e < 4; e++) o[4 + e] = f2b(b[e]);
    *(ushort8*)&out[i] = o;
}

// ---------------------------------------------------------------------------
// 1) 1024x1024 transpose + fp32->bf16 cast, 4 matrices via blockIdx.z
// ---------------------------------------------------------------------------
__global__ __launch_bounds__(256) void transpose_cast_kernel(
    const float* __restrict__ W0, const float* __restrict__ W1,
    const float* __restrict__ W2, const float* __restrict__ W3,
    ushort_t* __restrict__ T0, ushort_t* __restrict__ T1,
    ushort_t* __restrict__ T2, ushort_t* __restrict__ T3) {
    __shared__ ushort_t tile[32][33];
    const float* W;
    ushort_t* T;
    switch (blockIdx.z) {
        case 0: W = W0; T = T0; break;
        case 1: W = W1; T = T1; break;
        case 2: W = W2; T = T2; break;
        default: W = W3; T = T3; break;
    }
    int tx = threadIdx.x, ty = threadIdx.y;  // block (32,8)
    int x = blockIdx.x * 32 + tx;
    int ybase = blockIdx.y * 32 + ty;
#pragma unroll
    for (int r = 0; r < 4; r++) tile[ty + r * 8][tx] = f2b(W[(ybase + r * 8) * 1024 + x]);
    __syncthreads();
    int xo = blockIdx.y * 32 + tx;
    int yobase = blockIdx.x * 32 + ty;
#pragma unroll
    for (int r = 0; r < 4; r++) T[(yobase + r * 8) * 1024 + xo] = tile[tx][ty + r * 8];
}

// ---------------------------------------------------------------------------
// 2+4) GEMM: C[M,1024] = (A[M,1024] @ Bt^T + bias) * oscale
// Tile = (MF*32) x 128; 4 waves 2x2; global_load_lds staging; XCD swizzle.
// MODE 0 (QKV, MF=4, 768 blocks): xcd owns 8 m-blocks (2MB A) x 12 of 24
//   fused (z,ncol) columns (3MB B). zsel==2 (V) stores TRANSPOSED [B,H,hd,N].
// MODE 1 (out-proj, MF=2, 512 blocks): xcd owns 8 m-blocks x all 8 ncols.
// ---------------------------------------------------------------------------
template <typename OutT, int MODE, int MF>
__global__ __launch_bounds__(256) void gemm_bt_kernel(
    const ushort_t* __restrict__ A,
    const ushort_t* __restrict__ Bt0, const ushort_t* __restrict__ Bt1,
    const ushort_t* __restrict__ Bt2,
    const float* __restrict__ bias0, const float* __restrict__ bias1,
    const float* __restrict__ bias2,
    OutT* __restrict__ C0, OutT* __restrict__ C1, OutT* __restrict__ C2,
    float os0, float os1, float os2) {
    __shared__ ushort_t Al[MF * 32 * 64];
    __shared__ ushort_t Bl[128 * 64];

    // --- XCD-aware block decode ---
    const int id = blockIdx.x;
    const int xcd = id & 7;
    const int s = id >> 3;
    int m_blk, ncol, zsel;
    if (MODE == 0) {
        // s in [0,96): ncol-major outer (s>>3), m inner (s&7)
        m_blk = (xcd >> 1) * 8 + (s & 7);         // 0..31 (128-row blocks)
        ncol = (xcd & 1) * 12 + (s >> 3);         // 0..23 fused (z,x)
        zsel = ncol >> 3;
        ncol &= 7;
    } else {
        // s in [0,64): ncol-major outer (s>>3), m inner (s&7)
        m_blk = xcd * 8 + (s & 7);                // 0..63 (64-row blocks)
        ncol = s >> 3;                            // 0..7
        zsel = 0;
    }
    const int m0 = m_blk * (MF * 32);
    const int n0 = ncol * 128;

    const ushort_t* Bt;
    const float* bias;
    OutT* C;
    float oscale;
    if (zsel == 0) { Bt = Bt0; bias = bias0; C = C0; oscale = os0; }
    else if (zsel == 1) { Bt = Bt1; bias = bias1; C = C1; oscale = os1; }
    else { Bt = Bt2; bias = bias2; C = C2; oscale = os2; }

    const int tid = threadIdx.x;
    const int w = tid >> 6;
    const int l = tid & 63;
    const int wm = (w >> 1) * (MF * 16);
    const int wn = (w & 1) * 64;
    const int lrow = l & 15;
    const int lq = l >> 4;

    f32x4 acc[MF][4];
#pragma unroll
    for (int mi = 0; mi < MF; mi++)
#pragma unroll
        for (int ni = 0; ni < 4; ni++) acc[mi][ni] = 0.0f;

    for (int kt = 0; kt < 1024; kt += 64) {
#pragma unroll
        for (int t = 0; t < MF; t++) {
            int idx = t * 256 + tid;
            gload_lds16(&A[(long)(m0 + (idx >> 3)) * 1024 + kt + (idx & 7) * 8], &Al[idx * 8]);
        }
#pragma unroll
        for (int t = 0; t < 4; t++) {
            int idx = t * 256 + tid;
            gload_lds16(&Bt[(long)(n0 + (idx >> 3)) * 1024 + kt + (idx & 7) * 8], &Bl[idx * 8]);
        }
        __syncthreads();
#pragma unroll
        for (int ks = 0; ks < 64; ks += 32) {
            bf16x8 af[MF], bfr[4];
#pragma unroll
            for (int mi = 0; mi < MF; mi++)
                af[mi] = *(const bf16x8*)&Al[(wm + mi * 16 + lrow) * 64 + ks + lq * 8];
#pragma unroll
            for (int ni = 0; ni < 4; ni++)
                bfr[ni] = *(const bf16x8*)&Bl[(wn + ni * 16 + lrow) * 64 + ks + lq * 8];
#pragma unroll
            for (int mi = 0; mi < MF; mi++)
#pragma unroll
                for (int ni = 0; ni < 4; ni++)
                    acc[mi][ni] = __builtin_amdgcn_mfma_f32_16x16x32_bf16(
                        af[mi], bfr[ni], acc[mi][ni], 0, 0, 0);
        }
        __syncthreads();
    }

    // epilogue: C/D layout col=lane&15, row=(lane>>4)*4+reg
    if (MODE == 0 && zsel == 2) {
        // V projection: store transposed [B,H,hd,N]; n -> (h, d), m -> (b, i)
#pragma unroll
        for (int ni = 0; ni < 4; ni++) {
            int n = n0 + wn + ni * 16 + lrow;
            int h = n >> 6, d = n & 63;
            float bv = bias[n];
#pragma unroll
            for (int mi = 0; mi < MF; mi++) {
#pragma unroll
                for (int r = 0; r < 4; r++) {
                    int m = m0 + wm + mi * 16 + lq * 4 + r;
                    long dst = ((long)(((m >> 11) << 4) + h) * 64 + d) * 2048 + (m & 2047);
                    store_out(&C[dst], acc[mi][ni][r] + bv);
                }
            }
        }
    } else {
#pragma unroll
        for (int ni = 0; ni < 4; ni++) {
            int n = n0 + wn + ni * 16 + lrow;
            float bv = bias[n];
#pragma unroll
            for (int mi = 0; mi < MF; mi++) {
#pragma unroll
                for (int r = 0; r < 4; r++) {
                    int m = m0 + wm + mi * 16 + lq * 4 + r;
                    store_out(&C[(long)m * 1024 + n], (acc[mi][ni][r] + bv) * oscale);
                }
            }
        }
    }
}

// ---------------------------------------------------------------------------
// 3) Flash attention, window=256 causal. 1024 blocks, XCD-swizzled: xcd owns
// 4 (b,h) pairs. One block = (b, h, 64 q-rows); 4 waves x 16-row Q-tiles.
// V comes pre-transposed [B,H,hd,N]. Fixed-max softmax (Q pre-scaled 1/8),
// deferred row-sum. Staging: K via global_load_lds, V^T via ushort8+b128.
// ---------------------------------------------------------------------------
__global__ __launch_bounds__(256) void attn_kernel(
    const ushort_t* __restrict__ Q, const ushort_t* __restrict__ K,
    const ushort_t* __restrict__ VT, ushort_t* __restrict__ O) {
    __shared__ ushort_t Kl[128 * 64];    // K chunk, row-major [key][d]
    __shared__ ushort_t Vt[64 * 136];    // V^T chunk [d][key], padded stride
    __shared__ ushort_t Pb[4 * 16 * 40]; // per-wave P buffer [16 q][32 key]

    const int id = blockIdx.x;
    const int xcd = id & 7;
    const int s = id >> 3;               // 0..127
    const int bh = xcd * 4 + (s >> 5);   // 0..31
    const int b = bh >> 4;
    const int h = bh & 15;
    const int i0 = (s & 31) * 64;

    const int tid = threadIdx.x;
    const int w = tid >> 6;
    const int l = tid & 63;
    const int lrow = l & 15;
    const int lq = l >> 4;
    const int q0 = i0 + w * 16;

    const long baseBH = ((long)b * 2048) * 1024 + (long)h * 64;
    const long baseVT = (long)bh * 64 * 2048;

    // Q fragments (A-layout: m=l&15, k=lq*8+j), hd=64 -> 2 frags
    const ushort_t* qrow = Q + baseBH + (long)(q0 + lrow) * 1024;
    bf16x8 aq0 = *(const bf16x8*)&qrow[lq * 8];
    bf16x8 aq1 = *(const bf16x8*)&qrow[32 + lq * 8];

    float lpart[4];
    f32x4 oacc[4];
#pragma unroll
    for (int r = 0; r < 4; r++) lpart[r] = 0.0f;
#pragma unroll
    for (int ni = 0; ni < 4; ni++) oacc[ni] = 0.0f;

    const int kstart = (i0 - 256) > 0 ? (i0 - 256) : 0;
    const int kend = i0 + 64;
    ushort_t* Pw = &Pb[w * 16 * 40];

    for (int cs = kstart; cs < kend; cs += 128) {
        // stage K chunk [128 keys x 64 d] via global_load_lds; key clamped
        // (rows beyond kend are garbage but never read by compute)
#pragma unroll
        for (int t = 0; t < 4; t++) {
            int idx = t * 256 + tid;
            int key = cs + (idx >> 3);
            key = key < 2047 ? key : 2047;
            gload_lds16(&K[baseBH + (long)key * 1024 + (idx & 7) * 8], &Kl[idx * 8]);
        }
        // stage V^T chunk [64 d x 128 keys] -> padded [64][136]
#pragma unroll
        for (int j = 0; j < 4; j++) {
            int idx = j * 256 + tid;
            int d = idx >> 4;
            int kk = (idx & 15) * 8;
            int key = cs + kk;
            key = key <= 2040 ? key : 2040;
            ushort8 vv = *(const ushort8*)&VT[baseVT + (long)d * 2048 + key];
            *(ushort8*)&Vt[d * 136 + kk] = vv;
        }
        __syncthreads();

        const int ce = (cs + 128 < kend) ? cs + 128 : kend;
        for (int kb = cs; kb < ce; kb += 32) {
            if (kb > q0 + 15 || kb + 31 < q0 - 256) continue;  // fully masked
            const int rb = kb - cs;
            f32x4 S0 = 0.0f, S1 = 0.0f;
            {
                bf16x8 bk;
                bk = *(const bf16x8*)&Kl[(rb + lrow) * 64 + lq * 8];
                S0 = __builtin_amdgcn_mfma_f32_16x16x32_bf16(aq0, bk, S0, 0, 0, 0);
                bk = *(const bf16x8*)&Kl[(rb + lrow) * 64 + 32 + lq * 8];
                S0 = __builtin_amdgcn_mfma_f32_16x16x32_bf16(aq1, bk, S0, 0, 0, 0);
                bk = *(const bf16x8*)&Kl[(rb + 16 + lrow) * 64 + lq * 8];
                S1 = __builtin_amdgcn_mfma_f32_16x16x32_bf16(aq0, bk, S1, 0, 0, 0);
                bk = *(const bf16x8*)&Kl[(rb + 16 + lrow) * 64 + 32 + lq * 8];
                S1 = __builtin_amdgcn_mfma_f32_16x16x32_bf16(aq1, bk, S1, 0, 0, 0);
            }
            const int col0 = kb + lrow;
            const int col1 = kb + 16 + lrow;
#pragma unroll
            for (int r = 0; r < 4; r++) {
                const int i = q0 + lq * 4 + r;
                float p0 = (col0 > i || col0 < i - 256) ? 0.0f : exp2f(S0[r] * LOG2E);
                float p1 = (col1 > i || col1 < i - 256) ? 0.0f : exp2f(S1[r] * LOG2E);
                lpart[r] += p0 + p1;
                const int prow = lq * 4 + r;
                Pw[prow * 40 + lrow] = f2b(p0);
                Pw[prow * 40 + 16 + lrow] = f2b(p1);
            }
            // P: C-layout -> A-layout via LDS round-trip
            bf16x8 pf = *(const bf16x8*)&Pw[lrow * 40 + lq * 8];
#pragma unroll
            for (int ni = 0; ni < 4; ni++) {
                bf16x8 vf = *(const bf16x8*)&Vt[(ni * 16 + lrow) * 136 + rb + lq * 8];
                oacc[ni] = __builtin_amdgcn_mfma_f32_16x16x32_bf16(pf, vf, oacc[ni], 0, 0, 0);
            }
        }
        __syncthreads();
    }

    // deferred row-sum reduction (16-lane groups)
    float lS[4];
#pragma unroll
    for (int r = 0; r < 4; r++) {
        float rs = lpart[r];
#pragma unroll
        for (int off = 8; off; off >>= 1) rs += __shfl_xor(rs, off, 64);
        lS[r] = rs;
    }

#pragma unroll
    for (int ni = 0; ni < 4; ni++) {
#pragma unroll
        for (int r = 0; r < 4; r++) {
            const int i = q0 + lq * 4 + r;
            const int d = ni * 16 + lrow;
            O[baseBH + (long)i * 1024 + d] = f2b(oacc[ni][r] / lS[r]);
        }
    }
}

// ---------------------------------------------------------------------------
extern "C" void kernel_launch(void* const* d_in, const int* in_sizes, int n_in,
                              void* d_out, int out_size, void* d_ws, size_t ws_size,
                              hipStream_t stream) {
    const float* x  = (const float*)d_in[0];
    const float* Wq = (const float*)d_in[1];
    const float* bq = (const float*)d_in[2];
    const float* Wk = (const float*)d_in[3];
    const float* bk = (const float*)d_in[4];
    const float* Wv = (const float*)d_in[5];
    const float* bv = (const float*)d_in[6];
    const float* Wo = (const float*)d_in[7];
    const float* bo = (const float*)d_in[8];
    float* out = (float*)d_out;

    ushort_t* ws = (ushort_t*)d_ws;
    const size_t WMAT = (size_t)1024 * 1024;
    const size_t ACT = (size_t)2 * 2048 * 1024;
    ushort_t* xbf = ws;
    ushort_t* Wqt = xbf + ACT;
    ushort_t* Wkt = Wqt + WMAT;
    ushort_t* Wvt = Wkt + WMAT;
    ushort_t* Wot = Wvt + WMAT;
    ushort_t* qws = Wot + WMAT;
    ushort_t* kws = qws + ACT;
    ushort_t* vtws = kws + ACT;   // V^T layout [B,H,hd,N]
    ushort_t* aws = xbf;          // attO aliases xbf (x dead after QKV)

    // 0) cast x to bf16
    cast_f32_bf16_kernel<<<dim3((unsigned)(ACT / 2048)), 256, 0, stream>>>(x, xbf);

    // 1) transpose+cast the 4 weight matrices
    transpose_cast_kernel<<<dim3(32, 32, 4), dim3(32, 8), 0, stream>>>(
        Wq, Wk, Wv, Wo, Wqt, Wkt, Wvt, Wot);

    // 2) fused QKV projection, 128x128 tiles, XCD-swizzled 768-block grid.
    //    Q pre-scaled by 1/8; V written transposed.
    gemm_bt_kernel<ushort_t, 0, 4><<<768, 256, 0, stream>>>(
        xbf, Wqt, Wkt, Wvt, bq, bk, bv, qws, kws, vtws, 0.125f, 1.0f, 1.0f);

    // 3) windowed causal attention, XCD-swizzled 1024-block grid
    attn_kernel<<<1024, 256, 0, stream>>>(qws, kws, vtws, aws);

    // 4) output projection, 64x128 tiles, XCD-swizzled 512-block grid
    gemm_bt_kernel<float, 1, 2><<<512, 256, 0, stream>>>(
        aws, Wot, Wot, Wot, bo, bo, bo, out, out, out, 1.0f, 1.0f, 1.0f);
}